// Round 1
// baseline (361.602 us; speedup 1.0000x reference)
//
#include <hip/hip_runtime.h>
#include <stdint.h>
#include <stddef.h>

#define SEQ 4096
#define DM 1024
#define DH 128
#define NB 4

typedef __attribute__((ext_vector_type(8))) short bf16x8;
typedef __attribute__((ext_vector_type(4))) float f32x4;

__device__ __forceinline__ unsigned short f2bf(float f) {
    union { float f; uint32_t u; } v; v.f = f;
    uint32_t u = v.u + 0x7FFF + ((v.u >> 16) & 1);   // round-to-nearest-even
    return (unsigned short)(u >> 16);
}

__device__ __forceinline__ void gload_lds16(const void* g, void* l) {
    __builtin_amdgcn_global_load_lds(
        (const __attribute__((address_space(1))) void*)g,
        (__attribute__((address_space(3))) void*)l, 16, 0, 0);
}

// ---------------------------------------------------------------------------
// prep: cast x -> bf16 (xb), and build Wt[384][1024] = concat(Wq,Wk,Wv)^T bf16
// ---------------------------------------------------------------------------
__global__ __launch_bounds__(256) void prep_kernel(
    const float* __restrict__ x,
    const float* __restrict__ Wq, const float* __restrict__ Wk,
    const float* __restrict__ Wv,
    unsigned short* __restrict__ xb, unsigned short* __restrict__ Wt)
{
    int bid = blockIdx.x, tid = threadIdx.x;
    if (bid < 1536) {                       // 384*1024 / 256 = 1536 blocks
        int idx = bid * 256 + tid;
        int n = idx >> 10, k = idx & 1023;  // n in [0,384), k in [0,1024)
        int p = n >> 7, c = n & 127;
        const float* W = (p == 0) ? Wq : (p == 1) ? Wk : Wv;
        Wt[idx] = f2bf(W[k * DH + c]);
    } else {
        size_t i = (size_t)(bid - 1536) * 256 + tid;   // [0, 2097152)
        const float* src = x + i * 8;
        bf16x8 o;
        #pragma unroll
        for (int j = 0; j < 8; ++j) o[j] = (short)f2bf(src[j]);
        *(bf16x8*)(xb + i * 8) = o;
    }
}

// ---------------------------------------------------------------------------
// proj: [16384,1024] x [1024,384] -> q,k (row-major bf16) and v (transposed:
// vt[b][d][s]). 128x128 tile, BK=64, 4 waves (2x2), global_load_lds staging.
// ---------------------------------------------------------------------------
__global__ __launch_bounds__(256) void proj_kernel(
    const unsigned short* __restrict__ xb,   // [16384][1024]
    const unsigned short* __restrict__ Wt,   // [384][1024]
    const float* __restrict__ bq, const float* __restrict__ bk,
    const float* __restrict__ bv,
    unsigned short* __restrict__ qb, unsigned short* __restrict__ kb,
    unsigned short* __restrict__ vt)         // [4][128][4096]
{
    __shared__ unsigned short A_lds[128 * 64];
    __shared__ unsigned short B_lds[128 * 64];
    const int tid = threadIdx.x;
    const int lane = tid & 63, w = tid >> 6;
    const int wr = w >> 1, wc = w & 1;
    const int q15 = lane & 15, g = lane >> 4;
    const int mt = blockIdx.x & 127, nt = blockIdx.x >> 7;   // 128 x 3 blocks

    f32x4 acc[4][4];
    #pragma unroll
    for (int i = 0; i < 4; ++i)
        #pragma unroll
        for (int j2 = 0; j2 < 4; ++j2) acc[i][j2] = (f32x4){0.f, 0.f, 0.f, 0.f};

    const int arow = tid >> 3, aseg = tid & 7;   // arow in [0,32), 8 lanes/row
    for (int kt = 0; kt < 16; ++kt) {
        #pragma unroll
        for (int i = 0; i < 4; ++i) {
            gload_lds16(xb + ((size_t)(mt * 128 + arow + i * 32) * DM + kt * 64 + aseg * 8),
                        (char*)A_lds + w * 1024 + i * 4096);
            gload_lds16(Wt + ((size_t)(nt * 128 + arow + i * 32) * DM + kt * 64 + aseg * 8),
                        (char*)B_lds + w * 1024 + i * 4096);
        }
        __syncthreads();
        #pragma unroll
        for (int kk = 0; kk < 2; ++kk) {
            bf16x8 af[4], bf[4];
            #pragma unroll
            for (int mi = 0; mi < 4; ++mi)
                af[mi] = *(const bf16x8*)&A_lds[(wr * 64 + mi * 16 + q15) * 64 + kk * 32 + g * 8];
            #pragma unroll
            for (int ni = 0; ni < 4; ++ni)
                bf[ni] = *(const bf16x8*)&B_lds[(wc * 64 + ni * 16 + q15) * 64 + kk * 32 + g * 8];
            #pragma unroll
            for (int mi = 0; mi < 4; ++mi)
                #pragma unroll
                for (int ni = 0; ni < 4; ++ni)
                    acc[mi][ni] = __builtin_amdgcn_mfma_f32_16x16x32_bf16(
                        af[mi], bf[ni], acc[mi][ni], 0, 0, 0);
        }
        __syncthreads();
    }
    // epilogue: +bias, cast bf16, store (v goes out transposed)
    const float* bias = (nt == 0) ? bq : (nt == 1) ? bk : bv;
    unsigned short* dst = (nt == 0) ? qb : kb;
    #pragma unroll
    for (int ni = 0; ni < 4; ++ni) {
        int nloc = wc * 64 + ni * 16 + q15;           // [0,128)
        float bval = bias[nloc];
        #pragma unroll
        for (int mi = 0; mi < 4; ++mi) {
            int m0 = mt * 128 + wr * 64 + mi * 16 + g * 4;
            #pragma unroll
            for (int r = 0; r < 4; ++r) {
                unsigned short h = f2bf(acc[mi][ni][r] + bval);
                int m = m0 + r;
                if (nt < 2) dst[(size_t)m * DH + nloc] = h;
                else {
                    int b = m >> 12, s = m & 4095;
                    vt[(size_t)(b * 128 + nloc) * SEQ + s] = h;
                }
            }
        }
    }
}

// ---------------------------------------------------------------------------
// attn: flash-style causal attention. 256 blocks (b, qtile of 64 rows), 4
// waves x 16 q-rows. Swapped QK^T (mfma(K,Q) -> S^T) so softmax stats are
// lane-local; P transposed back via per-wave LDS. K_lds/V_lds padded +8.
// ---------------------------------------------------------------------------
__global__ __launch_bounds__(256) void attn_kernel(
    const unsigned short* __restrict__ qb,
    const unsigned short* __restrict__ kb,
    const unsigned short* __restrict__ vt,   // [4][128][4096]
    float* __restrict__ out)
{
    __shared__ unsigned short K_lds[64 * 136];   // [64 keys][128+8 d]
    __shared__ unsigned short V_lds[128 * 72];   // [128 d][64+8 keys] (=V^T)
    __shared__ unsigned short P_lds[4 * 16 * 72];// per-wave [16 q][64+8 k]
    const int tid = threadIdx.x;
    const int lane = tid & 63, w = tid >> 6;
    const int q15 = lane & 15, g = lane >> 4;
    // XCD-clustering: batch b maps to XCDs {2b, 2b+1}
    const int xcd = blockIdx.x & 7, slot = blockIdx.x >> 3;
    const int b = xcd >> 1;
    const int j = slot * 2 + (xcd & 1);          // q-tile index [0,64)
    const int qbase = j * 64;

    bf16x8 qf[4];
    const unsigned short* qrow = qb + (size_t)(b * SEQ + qbase + w * 16 + q15) * DH;
    #pragma unroll
    for (int kk = 0; kk < 4; ++kk) qf[kk] = *(const bf16x8*)(qrow + kk * 32 + g * 8);

    f32x4 o[8];
    #pragma unroll
    for (int f = 0; f < 8; ++f) o[f] = (f32x4){0.f, 0.f, 0.f, 0.f};
    float m_run = -__builtin_inff(), l_run = 0.f;
    const float scale = 0.08838834764831845f;    // 1/sqrt(128)
    const int qglob = qbase + w * 16 + q15;

    for (int kt = 0; kt <= j; ++kt) {
        {   // stage K tile and V^T tile (reg-staged: padded LDS rows)
            const unsigned short* ksrc = kb + (size_t)(b * SEQ + kt * 64) * DH;
            int krow = tid >> 4, kseg = tid & 15;
            #pragma unroll
            for (int i = 0; i < 4; ++i) {
                bf16x8 tmp = *(const bf16x8*)(ksrc + (size_t)(krow + i * 16) * DH + kseg * 8);
                *(bf16x8*)&K_lds[(krow + i * 16) * 136 + kseg * 8] = tmp;
            }
            const unsigned short* vsrc = vt + (size_t)(b * 128) * SEQ + kt * 64;
            int vrow = tid >> 3, vseg = tid & 7;
            #pragma unroll
            for (int i = 0; i < 4; ++i) {
                bf16x8 tmp = *(const bf16x8*)(vsrc + (size_t)(vrow + i * 32) * SEQ + vseg * 8);
                *(bf16x8*)&V_lds[(vrow + i * 32) * 72 + vseg * 8] = tmp;
            }
        }
        __syncthreads();
        // S^T = K * Q^T  (64 keys x 16 q); lane holds q-col q15, 16 key rows
        f32x4 sf[4];
        #pragma unroll
        for (int mt2 = 0; mt2 < 4; ++mt2) {
            f32x4 s = (f32x4){0.f, 0.f, 0.f, 0.f};
            #pragma unroll
            for (int kk = 0; kk < 4; ++kk) {
                bf16x8 kf = *(const bf16x8*)&K_lds[(mt2 * 16 + q15) * 136 + kk * 32 + g * 8];
                s = __builtin_amdgcn_mfma_f32_16x16x32_bf16(kf, qf[kk], s, 0, 0, 0);
            }
            sf[mt2] = s;
        }
        // mask + scale, tile max
        float tmax = -__builtin_inff();
        #pragma unroll
        for (int mt2 = 0; mt2 < 4; ++mt2)
            #pragma unroll
            for (int r = 0; r < 4; ++r) {
                int kglob = kt * 64 + mt2 * 16 + g * 4 + r;
                float v = sf[mt2][r] * scale;
                v = (kglob <= qglob) ? v : -__builtin_inff();
                sf[mt2][r] = v;
                tmax = fmaxf(tmax, v);
            }
        tmax = fmaxf(tmax, __shfl_xor(tmax, 16));
        tmax = fmaxf(tmax, __shfl_xor(tmax, 32));
        float m_new = fmaxf(m_run, tmax);
        float c = __expf(m_run - m_new);
        float rsum = 0.f;
        #pragma unroll
        for (int mt2 = 0; mt2 < 4; ++mt2)
            #pragma unroll
            for (int r = 0; r < 4; ++r) {
                float p = __expf(sf[mt2][r] - m_new);
                sf[mt2][r] = p;
                rsum += p;
            }
        rsum += __shfl_xor(rsum, 16);
        rsum += __shfl_xor(rsum, 32);
        l_run = l_run * c + rsum;
        m_run = m_new;
        // rescale O (c lives at lane q; O rows live at g*4+r)
        float cr[4];
        #pragma unroll
        for (int r = 0; r < 4; ++r) cr[r] = __shfl(c, g * 4 + r);
        #pragma unroll
        for (int f = 0; f < 8; ++f)
            #pragma unroll
            for (int r = 0; r < 4; ++r) o[f][r] *= cr[r];
        // pack P (bf16) into per-wave LDS, PV-A layout [q][k]
        uint32_t* pbase = (uint32_t*)&P_lds[(w * 16 + q15) * 72];
        #pragma unroll
        for (int mt2 = 0; mt2 < 4; ++mt2) {
            uint32_t p01 = (uint32_t)f2bf(sf[mt2][0]) | ((uint32_t)f2bf(sf[mt2][1]) << 16);
            uint32_t p23 = (uint32_t)f2bf(sf[mt2][2]) | ((uint32_t)f2bf(sf[mt2][3]) << 16);
            int e = mt2 * 16 + g * 4;
            pbase[e >> 1] = p01;
            pbase[(e >> 1) + 1] = p23;
        }
        // PV: o[q][d] += P[q][k] * V[k][d]  (B-frags read V^T rows contiguously)
        bf16x8 pf[2];
        #pragma unroll
        for (int kk2 = 0; kk2 < 2; ++kk2)
            pf[kk2] = *(const bf16x8*)&P_lds[(w * 16 + q15) * 72 + kk2 * 32 + g * 8];
        #pragma unroll
        for (int f = 0; f < 8; ++f)
            #pragma unroll
            for (int kk2 = 0; kk2 < 2; ++kk2) {
                bf16x8 vf = *(const bf16x8*)&V_lds[(f * 16 + q15) * 72 + kk2 * 32 + g * 8];
                o[f] = __builtin_amdgcn_mfma_f32_16x16x32_bf16(pf[kk2], vf, o[f], 0, 0, 0);
            }
        __syncthreads();
    }
    // normalize + store fp32
    float inv = 1.0f / l_run;
    float ir[4];
    #pragma unroll
    for (int r = 0; r < 4; ++r) ir[r] = __shfl(inv, g * 4 + r);
    float* ob = out + (size_t)(b * SEQ + qbase + w * 16) * DH;
    #pragma unroll
    for (int f = 0; f < 8; ++f)
        #pragma unroll
        for (int r = 0; r < 4; ++r)
            ob[(size_t)(g * 4 + r) * DH + f * 16 + q15] = o[f][r] * ir[r];
}

// ---------------------------------------------------------------------------
// Workspace layout (bytes):
//   xb  @ 0         : 16384*1024*2 = 33,554,432
//   Wt  @ 33554432  : 384*1024*2   =    786,432
//   qb  @ 34340864  : 16384*128*2  =  4,194,304
//   kb  @ 38535168  : 16384*128*2  =  4,194,304
//   vt  @ 42729472  : 4*128*4096*2 =  4,194,304
//   total ~46.9 MB
// ---------------------------------------------------------------------------
extern "C" void kernel_launch(void* const* d_in, const int* in_sizes, int n_in,
                              void* d_out, int out_size, void* d_ws, size_t ws_size,
                              hipStream_t stream)
{
    const float* x  = (const float*)d_in[0];
    const float* Wq = (const float*)d_in[1];
    const float* bq = (const float*)d_in[2];
    const float* Wk = (const float*)d_in[3];
    const float* bk = (const float*)d_in[4];
    const float* Wv = (const float*)d_in[5];
    const float* bv = (const float*)d_in[6];

    char* ws = (char*)d_ws;
    unsigned short* xb = (unsigned short*)(ws);
    unsigned short* Wt = (unsigned short*)(ws + 33554432);
    unsigned short* qb = (unsigned short*)(ws + 34340864);
    unsigned short* kb = (unsigned short*)(ws + 38535168);
    unsigned short* vt = (unsigned short*)(ws + 42729472);

    prep_kernel<<<9728, 256, 0, stream>>>(x, Wq, Wk, Wv, xb, Wt);
    proj_kernel<<<384, 256, 0, stream>>>(xb, Wt, bq, bk, bv, qb, kb, vt);
    attn_kernel<<<256, 256, 0, stream>>>(qb, kb, vt, (float*)d_out);
}

// Round 2
// 198.917 us; speedup vs baseline: 1.8179x; 1.8179x over previous
//
#include <hip/hip_runtime.h>
#include <stdint.h>
#include <stddef.h>

#define SEQ 4096
#define DM 1024
#define DH 128
#define NB 4
#define SPLITS 4

typedef __attribute__((ext_vector_type(8))) short bf16x8;
typedef __attribute__((ext_vector_type(4))) float f32x4;

__device__ __forceinline__ unsigned short f2bf(float f) {
    union { float f; uint32_t u; } v; v.f = f;
    uint32_t u = v.u + 0x7FFF + ((v.u >> 16) & 1);   // round-to-nearest-even
    return (unsigned short)(u >> 16);
}

__device__ __forceinline__ void gload_lds16(const void* g, void* l) {
    __builtin_amdgcn_global_load_lds(
        (const __attribute__((address_space(1))) void*)g,
        (__attribute__((address_space(3))) void*)l, 16, 0, 0);
}

// ---------------------------------------------------------------------------
// prep: cast x -> bf16 (xb), and build Wt[384][1024] = concat(Wq,Wk,Wv)^T bf16
// ---------------------------------------------------------------------------
__global__ __launch_bounds__(256) void prep_kernel(
    const float* __restrict__ x,
    const float* __restrict__ Wq, const float* __restrict__ Wk,
    const float* __restrict__ Wv,
    unsigned short* __restrict__ xb, unsigned short* __restrict__ Wt)
{
    int bid = blockIdx.x, tid = threadIdx.x;
    if (bid < 1536) {                       // 384*1024 / 256 = 1536 blocks
        int idx = bid * 256 + tid;
        int n = idx >> 10, k = idx & 1023;  // n in [0,384), k in [0,1024)
        int p = n >> 7, c = n & 127;
        const float* W = (p == 0) ? Wq : (p == 1) ? Wk : Wv;
        Wt[idx] = f2bf(W[k * DH + c]);
    } else {
        size_t i = (size_t)(bid - 1536) * 256 + tid;   // [0, 2097152)
        const float* src = x + i * 8;
        bf16x8 o;
        #pragma unroll
        for (int j = 0; j < 8; ++j) o[j] = (short)f2bf(src[j]);
        *(bf16x8*)(xb + i * 8) = o;
    }
}

// ---------------------------------------------------------------------------
// proj: [16384,1024] x [1024,384] -> q,k (row-major bf16) and v (transposed:
// vt[b][d][s]). 128x128 tile, BK=64, 4 waves (2x2), global_load_lds staging.
// ---------------------------------------------------------------------------
__global__ __launch_bounds__(256) void proj_kernel(
    const unsigned short* __restrict__ xb,   // [16384][1024]
    const unsigned short* __restrict__ Wt,   // [384][1024]
    const float* __restrict__ bq, const float* __restrict__ bk,
    const float* __restrict__ bv,
    unsigned short* __restrict__ qb, unsigned short* __restrict__ kb,
    unsigned short* __restrict__ vt)         // [4][128][4096]
{
    __shared__ unsigned short A_lds[128 * 64];
    __shared__ unsigned short B_lds[128 * 64];
    const int tid = threadIdx.x;
    const int lane = tid & 63, w = tid >> 6;
    const int wr = w >> 1, wc = w & 1;
    const int q15 = lane & 15, g = lane >> 4;
    const int mt = blockIdx.x & 127, nt = blockIdx.x >> 7;   // 128 x 3 blocks

    f32x4 acc[4][4];
    #pragma unroll
    for (int i = 0; i < 4; ++i)
        #pragma unroll
        for (int j2 = 0; j2 < 4; ++j2) acc[i][j2] = (f32x4){0.f, 0.f, 0.f, 0.f};

    const int arow = tid >> 3, aseg = tid & 7;   // arow in [0,32), 8 lanes/row
    for (int kt = 0; kt < 16; ++kt) {
        #pragma unroll
        for (int i = 0; i < 4; ++i) {
            gload_lds16(xb + ((size_t)(mt * 128 + arow + i * 32) * DM + kt * 64 + aseg * 8),
                        (char*)A_lds + w * 1024 + i * 4096);
            gload_lds16(Wt + ((size_t)(nt * 128 + arow + i * 32) * DM + kt * 64 + aseg * 8),
                        (char*)B_lds + w * 1024 + i * 4096);
        }
        __syncthreads();
        #pragma unroll
        for (int kk = 0; kk < 2; ++kk) {
            bf16x8 af[4], bfr[4];
            #pragma unroll
            for (int mi = 0; mi < 4; ++mi)
                af[mi] = *(const bf16x8*)&A_lds[(wr * 64 + mi * 16 + q15) * 64 + kk * 32 + g * 8];
            #pragma unroll
            for (int ni = 0; ni < 4; ++ni)
                bfr[ni] = *(const bf16x8*)&B_lds[(wc * 64 + ni * 16 + q15) * 64 + kk * 32 + g * 8];
            #pragma unroll
            for (int mi = 0; mi < 4; ++mi)
                #pragma unroll
                for (int ni = 0; ni < 4; ++ni)
                    acc[mi][ni] = __builtin_amdgcn_mfma_f32_16x16x32_bf16(
                        af[mi], bfr[ni], acc[mi][ni], 0, 0, 0);
        }
        __syncthreads();
    }
    // epilogue: +bias, cast bf16, store (v goes out transposed)
    const float* bias = (nt == 0) ? bq : (nt == 1) ? bk : bv;
    unsigned short* dst = (nt == 0) ? qb : kb;
    #pragma unroll
    for (int ni = 0; ni < 4; ++ni) {
        int nloc = wc * 64 + ni * 16 + q15;           // [0,128)
        float bval = bias[nloc];
        #pragma unroll
        for (int mi = 0; mi < 4; ++mi) {
            int m0 = mt * 128 + wr * 64 + mi * 16 + g * 4;
            #pragma unroll
            for (int r = 0; r < 4; ++r) {
                unsigned short h = f2bf(acc[mi][ni][r] + bval);
                int m = m0 + r;
                if (nt < 2) dst[(size_t)m * DH + nloc] = h;
                else {
                    int b = m >> 12, s = m & 4095;
                    vt[(size_t)(b * 128 + nloc) * SEQ + s] = h;
                }
            }
        }
    }
}

// ---------------------------------------------------------------------------
// attn pass 1: flash-style causal attention with K-range SPLITS (flash-
// decoding). Grid = 4 b x 64 qtiles x 4 splits = 1024 blocks (3/CU resident,
// dynamic draining balances the causal triangle). Per block: 4 waves x 16
// q-rows. Swapped QK^T (mfma(K,Q)) -> lane-local softmax stats. Reg-staged
// K/V prefetch hides global latency under compute. Defer-max (THR=8) skips
// most O-rescales. Writes UNNORMALIZED partial O + (m,l) per row.
// ---------------------------------------------------------------------------
__global__ __launch_bounds__(256) void attn_kernel(
    const unsigned short* __restrict__ qb,
    const unsigned short* __restrict__ kb,
    const unsigned short* __restrict__ vt,   // [4][128][4096]
    float* __restrict__ po,                  // [4 s][4 b][4096][128]
    float* __restrict__ pm, float* __restrict__ pl)  // [4 s][4 b][4096]
{
    __shared__ unsigned short K_lds[64 * 136];   // [64 keys][128+8 d]
    __shared__ unsigned short V_lds[128 * 72];   // [128 d][64+8 keys] (=V^T)
    __shared__ unsigned short P_lds[4 * 16 * 72];// per-wave [16 q][64+8 k]
    const int tid = threadIdx.x;
    const int lane = tid & 63, w = tid >> 6;
    const int q15 = lane & 15, g = lane >> 4;
    // b-major, long-q-tiles-first issue order
    const int b = blockIdx.x >> 8;
    const int u = blockIdx.x & 255;
    const int j = 63 - (u >> 2);                 // q-tile index [0,64)
    const int s = u & 3;                         // split index
    const int n = j + 1;
    const int lo = (n * s) >> 2, hi = (n * (s + 1)) >> 2;
    if (lo >= hi) return;                        // empty split
    const int qbase = j * 64;

    bf16x8 qf[4];
    const unsigned short* qrow = qb + (size_t)(b * SEQ + qbase + w * 16 + q15) * DH;
    #pragma unroll
    for (int kk = 0; kk < 4; ++kk) qf[kk] = *(const bf16x8*)(qrow + kk * 32 + g * 8);

    f32x4 o[8];
    #pragma unroll
    for (int f = 0; f < 8; ++f) o[f] = (f32x4){0.f, 0.f, 0.f, 0.f};
    float m_run = -__builtin_inff(), l_run = 0.f;
    const float scale = 0.08838834764831845f;    // 1/sqrt(128)
    const int qglob = qbase + w * 16 + q15;

    // reg-staging addresses
    const int krow = tid >> 4, kseg = tid & 15;  // K: [64 rows][16 segs of 8]
    const int vrow = tid >> 3, vseg = tid & 7;   // V^T: [128 rows][8 segs of 8]
    const unsigned short* kbb = kb + (size_t)b * SEQ * DH;
    const unsigned short* vbb = vt + (size_t)b * 128 * SEQ;
    bf16x8 kreg[4], vreg[4];
    {
        const unsigned short* ksrc = kbb + (size_t)(lo * 64) * DH;
        const unsigned short* vsrc = vbb + lo * 64;
        #pragma unroll
        for (int i = 0; i < 4; ++i) {
            kreg[i] = *(const bf16x8*)(ksrc + (size_t)(krow + i * 16) * DH + kseg * 8);
            vreg[i] = *(const bf16x8*)(vsrc + (size_t)(vrow + i * 32) * SEQ + vseg * 8);
        }
    }

    for (int kt = lo; kt < hi; ++kt) {
        // commit staged regs to LDS
        #pragma unroll
        for (int i = 0; i < 4; ++i) {
            *(bf16x8*)&K_lds[(krow + i * 16) * 136 + kseg * 8] = kreg[i];
            *(bf16x8*)&V_lds[(vrow + i * 32) * 72 + vseg * 8] = vreg[i];
        }
        __syncthreads();
        // prefetch next tile into regs (latency hides under compute below)
        if (kt + 1 < hi) {
            const unsigned short* ksrc = kbb + (size_t)((kt + 1) * 64) * DH;
            const unsigned short* vsrc = vbb + (kt + 1) * 64;
            #pragma unroll
            for (int i = 0; i < 4; ++i) {
                kreg[i] = *(const bf16x8*)(ksrc + (size_t)(krow + i * 16) * DH + kseg * 8);
                vreg[i] = *(const bf16x8*)(vsrc + (size_t)(vrow + i * 32) * SEQ + vseg * 8);
            }
        }
        // S^T = K * Q^T  (64 keys x 16 q); lane holds q-col q15, 16 key rows
        f32x4 sf[4];
        #pragma unroll
        for (int mt2 = 0; mt2 < 4; ++mt2) {
            f32x4 sa = (f32x4){0.f, 0.f, 0.f, 0.f};
            #pragma unroll
            for (int kk = 0; kk < 4; ++kk) {
                bf16x8 kf = *(const bf16x8*)&K_lds[(mt2 * 16 + q15) * 136 + kk * 32 + g * 8];
                sa = __builtin_amdgcn_mfma_f32_16x16x32_bf16(kf, qf[kk], sa, 0, 0, 0);
            }
            sf[mt2] = sa;
        }
        // mask + scale, tile max
        float tmax = -__builtin_inff();
        #pragma unroll
        for (int mt2 = 0; mt2 < 4; ++mt2)
            #pragma unroll
            for (int r = 0; r < 4; ++r) {
                int kglob = kt * 64 + mt2 * 16 + g * 4 + r;
                float v = sf[mt2][r] * scale;
                v = (kglob <= qglob) ? v : -__builtin_inff();
                sf[mt2][r] = v;
                tmax = fmaxf(tmax, v);
            }
        tmax = fmaxf(tmax, __shfl_xor(tmax, 16));
        tmax = fmaxf(tmax, __shfl_xor(tmax, 32));
        // defer-max: only rescale when the running max grows by > 8
        if (!__all((tmax - m_run) <= 8.0f)) {
            float m_new = fmaxf(m_run, tmax);
            float c = __expf(m_run - m_new);
            float cr[4];
            #pragma unroll
            for (int r = 0; r < 4; ++r) cr[r] = __shfl(c, g * 4 + r);
            #pragma unroll
            for (int f = 0; f < 8; ++f)
                #pragma unroll
                for (int r = 0; r < 4; ++r) o[f][r] *= cr[r];
            l_run *= c;
            m_run = m_new;
        }
        float rsum = 0.f;
        #pragma unroll
        for (int mt2 = 0; mt2 < 4; ++mt2)
            #pragma unroll
            for (int r = 0; r < 4; ++r) {
                float p = __expf(sf[mt2][r] - m_run);
                sf[mt2][r] = p;
                rsum += p;
            }
        rsum += __shfl_xor(rsum, 16);
        rsum += __shfl_xor(rsum, 32);
        l_run += rsum;
        // pack P (bf16) into per-wave LDS, PV-A layout [q][k]
        uint32_t* pbase = (uint32_t*)&P_lds[(w * 16 + q15) * 72];
        #pragma unroll
        for (int mt2 = 0; mt2 < 4; ++mt2) {
            uint32_t p01 = (uint32_t)f2bf(sf[mt2][0]) | ((uint32_t)f2bf(sf[mt2][1]) << 16);
            uint32_t p23 = (uint32_t)f2bf(sf[mt2][2]) | ((uint32_t)f2bf(sf[mt2][3]) << 16);
            int e = mt2 * 16 + g * 4;
            pbase[e >> 1] = p01;
            pbase[(e >> 1) + 1] = p23;
        }
        // PV: o[q][d] += P[q][k] * V[k][d]  (B-frags read V^T rows contiguously)
        bf16x8 pf[2];
        #pragma unroll
        for (int kk2 = 0; kk2 < 2; ++kk2)
            pf[kk2] = *(const bf16x8*)&P_lds[(w * 16 + q15) * 72 + kk2 * 32 + g * 8];
        #pragma unroll
        for (int f = 0; f < 8; ++f)
            #pragma unroll
            for (int kk2 = 0; kk2 < 2; ++kk2) {
                bf16x8 vf = *(const bf16x8*)&V_lds[(f * 16 + q15) * 72 + kk2 * 32 + g * 8];
                o[f] = __builtin_amdgcn_mfma_f32_16x16x32_bf16(pf[kk2], vf, o[f], 0, 0, 0);
            }
        __syncthreads();
    }
    // store UNNORMALIZED partial O + stats
    float* pob = po + ((size_t)(s * NB + b) * SEQ + qbase + w * 16) * DH;
    #pragma unroll
    for (int f = 0; f < 8; ++f)
        #pragma unroll
        for (int r = 0; r < 4; ++r)
            pob[(size_t)(g * 4 + r) * DH + f * 16 + q15] = o[f][r];
    if (g == 0) {
        size_t sidx = (size_t)(s * NB + b) * SEQ + qbase + w * 16 + q15;
        pm[sidx] = m_run;
        pl[sidx] = l_run;
    }
}

// ---------------------------------------------------------------------------
// attn pass 2: combine the 4 split partials per row.
// out[b][q][d] = sum_s e^{m_s-M} O_s[d] / sum_s e^{m_s-M} l_s
// ---------------------------------------------------------------------------
__global__ __launch_bounds__(256) void reduce_kernel(
    const float* __restrict__ po, const float* __restrict__ pm,
    const float* __restrict__ pl, float* __restrict__ out)
{
    int r = blockIdx.x * 8 + (threadIdx.x >> 5);     // row [0,16384)
    int d0 = (threadIdx.x & 31) * 4;
    int b = r >> 12, q = r & 4095;
    int n = (q >> 6) + 1;
    float ms[SPLITS];
    float M = -__builtin_inff();
    #pragma unroll
    for (int s = 0; s < SPLITS; ++s) {
        int lo = (n * s) >> 2, hi = (n * (s + 1)) >> 2;
        if (hi > lo) {
            ms[s] = pm[(size_t)(s * NB + b) * SEQ + q];
            M = fmaxf(M, ms[s]);
        } else ms[s] = -__builtin_inff();
    }
    float L = 0.f;
    f32x4 acc = (f32x4){0.f, 0.f, 0.f, 0.f};
    #pragma unroll
    for (int s = 0; s < SPLITS; ++s) {
        int lo = (n * s) >> 2, hi = (n * (s + 1)) >> 2;
        if (hi > lo) {
            float wgt = __expf(ms[s] - M);
            L += wgt * pl[(size_t)(s * NB + b) * SEQ + q];
            f32x4 p = *(const f32x4*)&po[((size_t)(s * NB + b) * SEQ + q) * DH + d0];
            acc += wgt * p;
        }
    }
    float inv = 1.0f / L;
    *(f32x4*)&out[((size_t)(b * SEQ) + q) * DH + d0] = acc * inv;
}

// ---------------------------------------------------------------------------
// Workspace layout (bytes) — partials ALIAS dead regions (xb/Wt dead after
// proj, po/pm/pl written only by attn which runs after proj):
//   xb  @ 0         : 16384*1024*2 = 33,554,432   | po aliases (33,554,432 B)
//   Wt  @ 33554432  : 384*1024*2   =    786,432   | pm (262,144) + pl (262,144)
//   qb  @ 34340864  : 16384*128*2  =  4,194,304
//   kb  @ 38535168  : 16384*128*2  =  4,194,304
//   vt  @ 42729472  : 4*128*4096*2 =  4,194,304
//   total ~46.9 MB (unchanged)
// ---------------------------------------------------------------------------
extern "C" void kernel_launch(void* const* d_in, const int* in_sizes, int n_in,
                              void* d_out, int out_size, void* d_ws, size_t ws_size,
                              hipStream_t stream)
{
    const float* x  = (const float*)d_in[0];
    const float* Wq = (const float*)d_in[1];
    const float* bq = (const float*)d_in[2];
    const float* Wk = (const float*)d_in[3];
    const float* bk = (const float*)d_in[4];
    const float* Wv = (const float*)d_in[5];
    const float* bv = (const float*)d_in[6];

    char* ws = (char*)d_ws;
    unsigned short* xb = (unsigned short*)(ws);
    unsigned short* Wt = (unsigned short*)(ws + 33554432);
    unsigned short* qb = (unsigned short*)(ws + 34340864);
    unsigned short* kb = (unsigned short*)(ws + 38535168);
    unsigned short* vt = (unsigned short*)(ws + 42729472);
    float* po = (float*)(ws);                   // aliases xb (dead after proj)
    float* pm = (float*)(ws + 33554432);        // aliases Wt (dead after proj)
    float* pl = (float*)(ws + 33554432 + 262144);

    prep_kernel<<<9728, 256, 0, stream>>>(x, Wq, Wk, Wv, xb, Wt);
    proj_kernel<<<384, 256, 0, stream>>>(xb, Wt, bq, bk, bv, qb, kb, vt);
    attn_kernel<<<1024, 256, 0, stream>>>(qb, kb, vt, po, pm, pl);
    reduce_kernel<<<2048, 256, 0, stream>>>(po, pm, pl, (float*)d_out);
}